// Round 14
// baseline (63.657 us; speedup 1.0000x reference)
//
#include <hip/hip_runtime.h>
#include <cstddef>

#define T_LEN 4096
#define BATCH 4
#define HID   1024
#define NS    16
#define ROWS  (BATCH*T_LEN)   // 16384
#define CHUNK 16
#define NCH   (T_LEN/CHUNK)   // 256

// workspace float offsets
#define OFF_AD   0        // A_d [16][16]
#define OFF_P    1024     // P_j = A_d^(j+1), j=0..15   [16+][16][16]
#define OFF_BDH  16384    // B_d bf16 [16][1024] (8192 floats)
#define OFF_Q    32768    // Q_k = (A_d^16)^k, k=0..255 [256][16][16] (65536 f)
#define OFF_U    98304    // local states [16384][16]
#define OFF_LEND 360448   // chunk-end local states [4][256][16]

typedef __bf16 v8bf  __attribute__((ext_vector_type(8)));
typedef float  f32x4 __attribute__((ext_vector_type(4)));

// ---------- setup_bd: all blocks: dt, expm, phi1, Bd slice; P/Q tables ----------
__global__ __launch_bounds__(256) void setup_bd_kernel(const float* __restrict__ A,
                                                       const float* __restrict__ B,
                                                       const float* __restrict__ log_dt,
                                                       float* __restrict__ ws) {
    __shared__ float red[256], Ms[256], term[256], E[256], G[256];
    __shared__ float S2[6][256];   // A_d^(2^j), j=0..5
    __shared__ float T2[8][256];   // (A_d^16)^(2^j), j=0..7
    __shared__ float V0[256], V1[256];
    const int tid = threadIdx.x;
    const int bid = blockIdx.x;

    // dt = mean(exp(log_dt))
    float s = 0.f;
    for (int i = tid; i < HID; i += 256) s += expf(log_dt[i]);
    red[tid] = s;
    __syncthreads();
    for (int w2 = 128; w2 > 0; w2 >>= 1) {
        if (tid < w2) red[tid] += red[tid + w2];
        __syncthreads();
    }
    const float dt = red[0] * (1.f/1024.f);

    const int r = tid >> 4, c = tid & 15;
    const float ident = (r == c) ? 1.f : 0.f;
    Ms[tid]   = A[tid] * (dt * (1.f/64.f));
    term[tid] = ident;
    E[tid]    = ident;
    G[tid]    = ident;
    __syncthreads();
    for (int i = 1; i <= 12; ++i) {
        float v = 0.f;
        #pragma unroll
        for (int m = 0; m < NS; ++m) v += term[r*16+m] * Ms[m*16+c];
        v /= (float)i;
        __syncthreads();
        term[tid] = v;
        E[tid] += v;
        G[tid] += v * (1.f/(float)(i+1));
        __syncthreads();
    }
    for (int d = 0; d < 6; ++d) {
        float ge = 0.f, ee = 0.f;
        #pragma unroll
        for (int m = 0; m < NS; ++m) {
            ge += G[r*16+m] * (E[m*16+c] + ((m==c)?1.f:0.f));
            ee += E[r*16+m] * E[m*16+c];
        }
        __syncthreads();
        G[tid] = 0.5f * ge;
        E[tid] = ee;
        __syncthreads();
    }
    red[tid] = dt * G[tid];   // X = dt*phi1
    __syncthreads();

    // Bd slice (bf16)
    {
        const int idx = bid * 256 + tid;
        const int n = idx >> 10, h = idx & 1023;
        float a = 0.f;
        #pragma unroll
        for (int m = 0; m < NS; ++m) a += red[n*16+m] * B[m*HID + h];
        __bf16* bdh = (__bf16*)(ws + OFF_BDH);
        bdh[n*HID + h] = (__bf16)a;
    }

    // power-of-two chains
    S2[0][tid] = E[tid];
    __syncthreads();
    for (int j = 1; j < 6; ++j) {
        float v = 0.f;
        #pragma unroll
        for (int m = 0; m < NS; ++m) v += S2[j-1][r*16+m] * S2[j-1][m*16+c];
        S2[j][tid] = v;
        __syncthreads();
    }
    T2[0][tid] = S2[4][tid];   // A_d^16
    __syncthreads();
    for (int j = 1; j < 8; ++j) {
        float v = 0.f;
        #pragma unroll
        for (int m = 0; m < NS; ++m) v += T2[j-1][r*16+m] * T2[j-1][m*16+c];
        T2[j][tid] = v;
        __syncthreads();
    }

    if (bid == 0) ws[OFF_AD + tid] = E[tid];

    // P table: blocks 0..3 write P_{4b+1..4b+4} (A_d^1..16)
    if (bid < 4) {
        for (int v4 = 0; v4 < 4; ++v4) {
            const int j2 = 4*bid + v4 + 1;   // 1..16
            float* Vc = V0; float* Vn = V1;
            bool have = false;
            for (int bit = 0; bit < 5; ++bit) {
                if (!((j2 >> bit) & 1)) continue;
                if (!have) {
                    Vc[tid] = S2[bit][tid];
                    have = true;
                    __syncthreads();
                } else {
                    float v = 0.f;
                    #pragma unroll
                    for (int m = 0; m < NS; ++m) v += Vc[r*16+m] * S2[bit][m*16+c];
                    Vn[tid] = v;
                    __syncthreads();
                    float* t1 = Vc; Vc = Vn; Vn = t1;
                }
            }
            ws[OFF_P + (j2-1)*256 + tid] = Vc[tid];
            __syncthreads();
        }
    }
    // Q table: all 64 blocks write Q_{4b..4b+3} ((A_d^16)^0..255)
    {
        for (int v4 = 0; v4 < 4; ++v4) {
            const int k = 4*bid + v4;   // 0..255
            float* Vc = V0; float* Vn = V1;
            bool have = false;
            for (int bit = 0; bit < 8; ++bit) {
                if (!((k >> bit) & 1)) continue;
                if (!have) {
                    Vc[tid] = T2[bit][tid];
                    have = true;
                    __syncthreads();
                } else {
                    float v = 0.f;
                    #pragma unroll
                    for (int m = 0; m < NS; ++m) v += Vc[r*16+m] * T2[bit][m*16+c];
                    Vn[tid] = v;
                    __syncthreads();
                    float* t1 = Vc; Vc = Vn; Vn = t1;
                }
            }
            ws[OFF_Q + k*256 + tid] = have ? Vc[tid] : ident;
            __syncthreads();
        }
    }
}

// ---------- K1: u = x @ B_d^T via MFMA + 16-step local scan ----------
// 16 rows/block, grid 1024, 512 thr = 8 waves (8-way K-split, 128 K-cols each).
// 42 KB LDS -> 3 blocks/CU (24 waves/CU).
__global__ __launch_bounds__(512, 6) void k1_kernel(const float* __restrict__ x,
                                                    float* __restrict__ ws) {
    __shared__ __align__(16) float xs[2][16*256];  // 32 KB double buffer
    __shared__ __align__(16) float red[8*256];     // 8 KB
    __shared__ __align__(16) float us[16*16];      // 1 KB
    const int tid  = threadIdx.x;
    const int w    = tid >> 6;           // wave = ksub 0..7
    const int lane = tid & 63;
    const int row0 = blockIdx.x * 16;
    const int lr = lane & 15;
    const int hi = lane >> 4;
    const int swzr = (lr & 7) << 4;
    const int cb = w*128 + hi*32;        // within-stage byte col

    char* lds0 = (char*)&xs[0][0];
    char* lds1 = (char*)&xs[1][0];
    // staging: thread covers row tid>>5, 2x16B at byte cols (tid&31)*32 + {0,16}
    const int srow = tid >> 5;
    const int scol = (tid & 31) * 32;
    const int loff0 = srow*1024 + ((scol)      ^ ((srow & 7) << 4));
    const int loff1 = srow*1024 + ((scol + 16) ^ ((srow & 7) << 4));
    const float* gp = x + (size_t)(row0 + srow)*HID + (tid & 31)*8;

    {
        float4 s0 = *(const float4*)(gp);
        float4 s1 = *(const float4*)(gp + 4);
        *(float4*)(lds0 + loff0) = s0;
        *(float4*)(lds0 + loff1) = s1;
    }
    __syncthreads();

    f32x4 acc = {0.f, 0.f, 0.f, 0.f};
    const __bf16* bdh = (const __bf16*)(ws + OFF_BDH);
    const __bf16* bp  = bdh + (size_t)lr*HID + w*32 + hi*8;

    for (int s4 = 0; s4 < 4; ++s4) {
        float4 s0, s1;
        if (s4 < 3) {
            s0 = *(const float4*)(gp + (s4+1)*256);
            s1 = *(const float4*)(gp + (s4+1)*256 + 4);
        }
        const char* base = (s4 & 1) ? lds1 : lds0;
        {
            float4 a0 = *(const float4*)(base + lr*1024 + (cb ^ swzr));
            float4 a1 = *(const float4*)(base + lr*1024 + ((cb + 16) ^ swzr));
            v8bf a;
            a[0]=(__bf16)a0.x; a[1]=(__bf16)a0.y; a[2]=(__bf16)a0.z; a[3]=(__bf16)a0.w;
            a[4]=(__bf16)a1.x; a[5]=(__bf16)a1.y; a[6]=(__bf16)a1.z; a[7]=(__bf16)a1.w;
            v8bf bb = *(const v8bf*)(bp + s4*256);
            acc = __builtin_amdgcn_mfma_f32_16x16x32_bf16(a, bb, acc, 0, 0, 0);
        }
        if (s4 < 3) {
            char* dst = (s4 & 1) ? lds0 : lds1;
            *(float4*)(dst + loff0) = s0;
            *(float4*)(dst + loff1) = s1;
        }
        __syncthreads();
    }

    // stash per-wave 16x16 tile (D: row=(lane>>4)*4+reg, col=lane&15)
    #pragma unroll
    for (int rreg = 0; rreg < 4; ++rreg)
        red[w*256 + (hi*4 + rreg)*16 + lr] = acc[rreg];
    __syncthreads();
    // combine 8 k-slices
    if (tid < 256) {
        const int rowl = tid >> 4, n = tid & 15;
        float v = 0.f;
        #pragma unroll
        for (int kk = 0; kk < 8; ++kk)
            v += red[kk*256 + rowl*16 + n];
        us[tid] = v;
    }
    __syncthreads();
    // local scan over 16 steps (wave 0, m-split 4-way)
    if (tid < 64) {
        const int n = tid & 15, mg = tid >> 4;
        const float a0 = ws[OFF_AD + (mg*4+0)*16 + n];
        const float a1 = ws[OFF_AD + (mg*4+1)*16 + n];
        const float a2 = ws[OFF_AD + (mg*4+2)*16 + n];
        const float a3 = ws[OFF_AD + (mg*4+3)*16 + n];
        float v = 0.f;
        for (int t = 0; t < CHUNK; ++t) {
            const float u0 = us[t*16 + n];
            float q = __shfl(v, mg*4+0, 16)*a0 + __shfl(v, mg*4+1, 16)*a1
                    + __shfl(v, mg*4+2, 16)*a2 + __shfl(v, mg*4+3, 16)*a3;
            q += __shfl_xor(q, 16);
            q += __shfl_xor(q, 32);
            v = u0 + q;
            if (mg == 0) us[t*16 + n] = v;
        }
        if (mg == 0) {
            const int b = row0 >> 12, cch = (row0 >> 4) & (NCH-1);
            ws[OFF_LEND + (b*NCH + cch)*16 + n] = v;
        }
    }
    __syncthreads();
    if (tid < 64) {
        const int j = tid >> 2, nq = (tid & 3)*4;
        *(float4*)(ws + OFF_U + (size_t)(row0 + j)*16 + nq) = *(const float4*)(&us[j*16 + nq]);
    }
}

// ---------- K2: 2 chunks/block; cin0 via Q-sum, cin1 = cin0*Q1 + lend_c0;
//            correction with P_1..16; out = states @ C^T via MFMA ----------
__global__ __launch_bounds__(512, 4) void k2_kernel(const float* __restrict__ C,
                                                    const float* __restrict__ state,
                                                    const float* __restrict__ ws,
                                                    float* __restrict__ out) {
    __shared__ __align__(16) float st[32*20];     // padded stride 20
    __shared__ float vec[(NCH+1)*16];             // lend_0..c0-1, state0
    __shared__ float part[32*17];
    __shared__ float cin_s[32];                   // cin0 | cin1
    __shared__ float lc0_s[16];
    const int tid = threadIdx.x;
    const int row0 = blockIdx.x * 32;
    const int b = row0 >> 12;
    const int c0 = (row0 >> 4) & (NCH-1);         // even; c1 = c0+1

    // load local states (2 chunks = 32 rows)
    if (tid < 128) {
        const int j = tid >> 2, n4 = (tid & 3)*4;
        *(float4*)(&st[j*20 + n4]) =
            *(const float4*)(ws + OFF_U + (size_t)(row0 + j)*16 + n4);
    }
    // stage lend_0..c0-1 + state0 + lend_c0
    for (int i = tid; i < c0*16; i += 512)
        vec[i] = ws[OFF_LEND + b*NCH*16 + i];
    if (tid < 16) {
        vec[c0*16 + tid] = state[b*16 + tid];
        lc0_s[tid] = ws[OFF_LEND + (b*NCH + c0)*16 + tid];
    }
    __syncthreads();

    // cin0 = state0*Q_c0 + sum_j lend_j * Q_{c0-1-j}  (32 parallel groups)
    {
        const int g = tid >> 4, n2 = tid & 15;
        float p = 0.f;
        for (int j = g; j <= c0; j += 32) {
            const int qidx = (j == c0) ? c0 : (c0 - 1 - j);
            const float* Q = ws + OFF_Q + qidx*256;
            float sv = 0.f;
            #pragma unroll
            for (int m = 0; m < NS; ++m) sv += vec[j*16 + m] * Q[m*16 + n2];
            p += sv;
        }
        part[g*17 + n2] = p;
    }
    __syncthreads();
    for (int s2 = 16; s2 > 0; s2 >>= 1) {
        if ((tid >> 4) < s2)
            part[(tid>>4)*17 + (tid&15)] += part[((tid>>4)+s2)*17 + (tid&15)];
        __syncthreads();
    }
    if (tid < 16) cin_s[tid] = part[tid];
    __syncthreads();
    // cin1 = cin0 * Q_1 + lend_c0
    if (tid < 16) {
        const float* Q1 = ws + OFF_Q + 256;
        float v = lc0_s[tid];
        #pragma unroll
        for (int m = 0; m < NS; ++m) v += cin_s[m] * Q1[m*16 + tid];
        cin_s[16 + tid] = v;
    }
    __syncthreads();

    // correction: st[j] += cin(chunk) * P_{jj+1}
    if (tid < 128) {
        const int j = tid >> 2, n4 = (tid & 3)*4;
        const int ch = j >> 4, jj = j & 15;
        float4 ls = *(const float4*)(&st[j*20 + n4]);
        const float* P = ws + OFF_P + jj*256 + n4;
        const float* cin = &cin_s[ch*16];
        float cx=0.f, cy=0.f, cz=0.f, cw=0.f;
        #pragma unroll
        for (int m = 0; m < NS; ++m) {
            const float cm = cin[m];
            float4 pv = *(const float4*)(P + m*16);
            cx += cm*pv.x; cy += cm*pv.y; cz += cm*pv.z; cw += cm*pv.w;
        }
        *(float4*)(&st[j*20 + n4]) = make_float4(ls.x+cx, ls.y+cy, ls.z+cz, ls.w+cw);
    }
    __syncthreads();
    if (c0 == NCH-2 && tid < 16)
        out[(size_t)ROWS*HID + b*16 + tid] = st[31*20 + tid];

    // out = states @ C^T via MFMA (8 waves: rhalf = w&1, colgroup = w>>1)
    const int w = tid >> 6, lane = tid & 63;
    const int rhalf = w & 1, cg = w >> 1;
    const int lr = lane & 15;
    const int hi = lane >> 4;
    const int lk = hi * 8;   // 0,8 real; 16,24 -> zero

    v8bf afr = {};
    if (lk < 16) {
        float4 s0 = *(const float4*)(&st[(rhalf*16 + lr)*20 + lk]);
        float4 s1 = *(const float4*)(&st[(rhalf*16 + lr)*20 + lk + 4]);
        afr[0]=(__bf16)s0.x; afr[1]=(__bf16)s0.y; afr[2]=(__bf16)s0.z; afr[3]=(__bf16)s0.w;
        afr[4]=(__bf16)s1.x; afr[5]=(__bf16)s1.y; afr[6]=(__bf16)s1.z; afr[7]=(__bf16)s1.w;
    }
    const int orow = row0 + rhalf*16 + hi*4;

    float4 pc0, pc1;
    {
        const int n0 = (cg*16)*16;
        if (lk < 16) {
            pc0 = *(const float4*)(C + (size_t)(n0 + lr)*16 + lk);
            pc1 = *(const float4*)(C + (size_t)(n0 + lr)*16 + lk + 4);
        }
    }
    #pragma unroll 4
    for (int nt = 0; nt < 16; ++nt) {
        const int n0 = (cg*16 + nt)*16;
        float4 c0v = pc0, c1v = pc1;
        if (nt + 1 < 16 && lk < 16) {
            const int n1 = (cg*16 + nt + 1)*16;
            pc0 = *(const float4*)(C + (size_t)(n1 + lr)*16 + lk);
            pc1 = *(const float4*)(C + (size_t)(n1 + lr)*16 + lk + 4);
        }
        v8bf bfr = {};
        if (lk < 16) {
            bfr[0]=(__bf16)c0v.x; bfr[1]=(__bf16)c0v.y; bfr[2]=(__bf16)c0v.z; bfr[3]=(__bf16)c0v.w;
            bfr[4]=(__bf16)c1v.x; bfr[5]=(__bf16)c1v.y; bfr[6]=(__bf16)c1v.z; bfr[7]=(__bf16)c1v.w;
        }
        f32x4 acc2 = {0.f, 0.f, 0.f, 0.f};
        acc2 = __builtin_amdgcn_mfma_f32_16x16x32_bf16(afr, bfr, acc2, 0, 0, 0);
        #pragma unroll
        for (int rg = 0; rg < 4; ++rg)
            out[(size_t)(orow + rg)*HID + n0 + lr] = acc2[rg];
    }
}

extern "C" void kernel_launch(void* const* d_in, const int* in_sizes, int n_in,
                              void* d_out, int out_size, void* d_ws, size_t ws_size,
                              hipStream_t stream) {
    (void)in_sizes; (void)n_in; (void)out_size; (void)ws_size;
    const float* x      = (const float*)d_in[0];
    const float* state  = (const float*)d_in[1];
    const float* A      = (const float*)d_in[2];
    const float* B      = (const float*)d_in[3];
    const float* C      = (const float*)d_in[4];
    const float* log_dt = (const float*)d_in[5];
    float* out = (float*)d_out;
    float* ws  = (float*)d_ws;

    setup_bd_kernel<<<64, 256, 0, stream>>>(A, B, log_dt, ws);
    k1_kernel      <<<ROWS/16, 512, 0, stream>>>(x, ws);
    k2_kernel      <<<ROWS/32, 512, 0, stream>>>(C, state, ws, out);
}

// Round 15
// 53.660 us; speedup vs baseline: 1.1863x; 1.1863x over previous
//
#include <hip/hip_runtime.h>
#include <cstddef>

#define T_LEN 4096
#define BATCH 4
#define HID   1024
#define NS    16
#define ROWS  (BATCH*T_LEN)   // 16384
#define CHUNK 32
#define NCH   (T_LEN/CHUNK)   // 128

// workspace float offsets
#define OFF_P    1024     // P_j = A_d^(j+1), j=0..31   [32][16][16]
#define OFF_Q    32768    // Q_k = (A_d^32)^k, k=0..127 [128][16][16]
#define OFF_U    65536    // local states [16384][16]
#define OFF_LEND 327680   // chunk-end local states [4][128][16]

typedef __bf16 v8bf  __attribute__((ext_vector_type(8)));
typedef float  f32x4 __attribute__((ext_vector_type(4)));

// ---------- K1 fused: per-block setup (dt, expm, phi1, Bd) + MFMA-u + scan;
//            blocks 0..39 also emit P/Q tables ----------
__global__ __launch_bounds__(512, 4) void k1_fused(const float* __restrict__ x,
                                                   const float* __restrict__ A,
                                                   const float* __restrict__ B,
                                                   const float* __restrict__ log_dt,
                                                   float* __restrict__ ws) {
    __shared__ __align__(16) float xs[2][32*256];  // 64 KB: setup scratch -> x dbuf
    __shared__ __align__(16) float red[8*256];     // 8 KB: dt reduce -> MFMA tiles
    __shared__ __align__(16) float us[32*16];      // 2 KB
    __shared__ float Adl[256], Xl[256], Esv[256];  // 3 KB persistent
    const int tid  = threadIdx.x;
    const int w    = tid >> 6;
    const int lane = tid & 63;
    const int bid  = blockIdx.x;
    const int row0 = bid * 32;
    const int rhalf = w & 1;
    const int ksub  = w >> 1;
    const int lr = lane & 15;
    const int hi = lane >> 4;
    const int r  = rhalf*16 + lr;
    const int swzr = (r & 7) << 4;
    const int r16 = (tid >> 4) & 15, c16 = tid & 15;
    const float ident = (r16 == c16) ? 1.f : 0.f;

    // ---- phase 0a: dt = mean(exp(log_dt)) ----
    red[tid] = expf(log_dt[tid]) + expf(log_dt[tid + 512]);
    __syncthreads();
    for (int w2 = 256; w2 > 0; w2 >>= 1) {
        if (tid < w2) red[tid] += red[tid + w2];
        __syncthreads();
    }
    const float dt = red[0] * (1.f/1024.f);

    // ---- phase 0b: Taylor-12 + 6 doublings (tid<256), ping-pong term ----
    float* Ms = &xs[0][0];
    float* t0 = &xs[0][256];
    float* t1 = &xs[0][512];
    float* E  = &xs[0][768];
    float* G  = &xs[0][1024];
    if (tid < 256) {
        Ms[tid] = A[tid] * (dt * (1.f/64.f));
        t0[tid] = ident;
        E[tid]  = ident;
        G[tid]  = ident;
    }
    __syncthreads();
    {
        float* tc = t0; float* tn = t1;
        for (int i = 1; i <= 12; ++i) {
            if (tid < 256) {
                float v = 0.f;
                #pragma unroll
                for (int m = 0; m < NS; ++m) v += tc[r16*16+m] * Ms[m*16+c16];
                v /= (float)i;
                tn[tid] = v;
                E[tid] += v;
                G[tid] += v * (1.f/(float)(i+1));
            }
            __syncthreads();
            float* tt = tc; tc = tn; tn = tt;
        }
    }
    for (int d = 0; d < 6; ++d) {
        float ge = 0.f, ee = 0.f;
        if (tid < 256) {
            #pragma unroll
            for (int m = 0; m < NS; ++m) {
                ge += G[r16*16+m] * (E[m*16+c16] + ((m==c16)?1.f:0.f));
                ee += E[r16*16+m] * E[m*16+c16];
            }
        }
        __syncthreads();
        if (tid < 256) {
            G[tid] = 0.5f * ge;
            E[tid] = ee;
        }
        __syncthreads();
    }
    if (tid < 256) {
        Adl[tid] = E[tid];
        Xl[tid]  = dt * G[tid];
        Esv[tid] = E[tid];
    }
    __syncthreads();

    // ---- phase 0c: Bd bf16 into xs[1]; 1 col/thread x2 (B coalesced, X broadcast) ----
    __bf16* Bdl = (__bf16*)&xs[1][0];
    {
        float o0[16], o1[16];
        #pragma unroll
        for (int n = 0; n < 16; ++n) { o0[n] = 0.f; o1[n] = 0.f; }
        for (int m = 0; m < NS; ++m) {
            const float b0 = B[m*HID + tid];
            const float b1 = B[m*HID + tid + 512];
            #pragma unroll
            for (int n = 0; n < 16; ++n) {
                const float xv = Xl[n*16 + m];
                o0[n] += xv * b0;
                o1[n] += xv * b1;
            }
        }
        #pragma unroll
        for (int n = 0; n < 16; ++n) {
            Bdl[n*HID + tid]       = (__bf16)o0[n];
            Bdl[n*HID + tid + 512] = (__bf16)o1[n];
        }
    }
    __syncthreads();
    // hoist Bd fragments to registers
    v8bf bfr[8];
    #pragma unroll
    for (int s4 = 0; s4 < 4; ++s4)
        #pragma unroll
        for (int kk2 = 0; kk2 < 2; ++kk2)
            bfr[s4*2+kk2] = *(const v8bf*)(Bdl + (size_t)lr*HID + s4*256 + (ksub*2+kk2)*32 + hi*8);
    __syncthreads();

    // ---- phase 1: u = x @ Bd^T (round-11 2-phase staged schedule) ----
    char* lds0 = (char*)&xs[0][0];
    char* lds1 = (char*)&xs[1][0];
    int loff[4];
    const float* gp[4];
    #pragma unroll
    for (int i = 0; i < 4; ++i) {
        const int row = w*4 + i;
        loff[i] = row*1024 + ((lane*16) ^ ((row & 7) << 4));
        gp[i] = x + (size_t)(row0 + row)*HID + lane*4;
    }
    {
        float4 stg[4];
        #pragma unroll
        for (int i = 0; i < 4; ++i) stg[i] = *(const float4*)(gp[i]);
        #pragma unroll
        for (int i = 0; i < 4; ++i) *(float4*)(lds0 + loff[i]) = stg[i];
    }
    __syncthreads();
    f32x4 acc = {0.f, 0.f, 0.f, 0.f};
    for (int s4 = 0; s4 < 4; ++s4) {
        float4 stg[4];
        if (s4 < 3) {
            #pragma unroll
            for (int i = 0; i < 4; ++i)
                stg[i] = *(const float4*)(gp[i] + (s4+1)*256);
        }
        const char* base = (s4 & 1) ? lds1 : lds0;
        #pragma unroll
        for (int kk2 = 0; kk2 < 2; ++kk2) {
            const int kk = ksub*2 + kk2;
            const int colb = kk*128 + hi*32;
            float4 a0 = *(const float4*)(base + r*1024 + (colb ^ swzr));
            float4 a1 = *(const float4*)(base + r*1024 + ((colb + 16) ^ swzr));
            v8bf a;
            a[0]=(__bf16)a0.x; a[1]=(__bf16)a0.y; a[2]=(__bf16)a0.z; a[3]=(__bf16)a0.w;
            a[4]=(__bf16)a1.x; a[5]=(__bf16)a1.y; a[6]=(__bf16)a1.z; a[7]=(__bf16)a1.w;
            acc = __builtin_amdgcn_mfma_f32_16x16x32_bf16(a, bfr[s4*2+kk2], acc, 0, 0, 0);
        }
        if (s4 < 3) {
            char* dst = (s4 & 1) ? lds0 : lds1;
            #pragma unroll
            for (int i = 0; i < 4; ++i) *(float4*)(dst + loff[i]) = stg[i];
        }
        __syncthreads();
    }
    #pragma unroll
    for (int rreg = 0; rreg < 4; ++rreg)
        red[w*256 + (hi*4 + rreg)*16 + lr] = acc[rreg];
    __syncthreads();
    {   // combine 4 k-slices
        const int rowl = tid >> 4, n = tid & 15;
        const int rh = rowl >> 4, rl = rowl & 15;
        float v = 0.f;
        #pragma unroll
        for (int kk = 0; kk < 4; ++kk)
            v += red[(rh + 2*kk)*256 + rl*16 + n];
        us[tid] = v;
    }
    __syncthreads();
    // local scan over 32 steps (wave 0, m-split 4-way; A_d from LDS)
    if (tid < 64) {
        const int n = tid & 15, mg = tid >> 4;
        const float a0 = Adl[(mg*4+0)*16 + n];
        const float a1 = Adl[(mg*4+1)*16 + n];
        const float a2 = Adl[(mg*4+2)*16 + n];
        const float a3 = Adl[(mg*4+3)*16 + n];
        float v = 0.f;
        for (int t = 0; t < CHUNK; ++t) {
            const float u0 = us[t*16 + n];
            float q = __shfl(v, mg*4+0, 16)*a0 + __shfl(v, mg*4+1, 16)*a1
                    + __shfl(v, mg*4+2, 16)*a2 + __shfl(v, mg*4+3, 16)*a3;
            q += __shfl_xor(q, 16);
            q += __shfl_xor(q, 32);
            v = u0 + q;
            if (mg == 0) us[t*16 + n] = v;
        }
        if (mg == 0) {
            const int b = row0 >> 12, cch = (row0 >> 5) & (NCH-1);
            ws[OFF_LEND + (b*NCH + cch)*16 + n] = v;
        }
    }
    __syncthreads();
    if (tid < 128) {
        const int j = tid >> 2, nq = (tid & 3)*4;
        *(float4*)(ws + OFF_U + (size_t)(row0 + j)*16 + nq) = *(const float4*)(&us[j*16 + nq]);
    }

    // ---- phase 2 (blocks 0..39): P/Q tables via binary powering ----
    if (bid < 40) {
        __syncthreads();
        float* S2 = &xs[0][0];          // 6 x 256: A_d^(2^j)
        float* T2 = &xs[0][1536];       // 7 x 256: (A_d^32)^(2^j)
        float* V0 = &xs[0][3328];
        float* V1 = &xs[0][3584];
        if (tid < 256) S2[tid] = Esv[tid];
        __syncthreads();
        for (int j = 1; j < 6; ++j) {
            if (tid < 256) {
                float v = 0.f;
                #pragma unroll
                for (int m = 0; m < NS; ++m)
                    v += S2[(j-1)*256 + r16*16+m] * S2[(j-1)*256 + m*16+c16];
                S2[j*256 + tid] = v;
            }
            __syncthreads();
        }
        if (tid < 256) T2[tid] = S2[5*256 + tid];
        __syncthreads();
        for (int j = 1; j < 7; ++j) {
            if (tid < 256) {
                float v = 0.f;
                #pragma unroll
                for (int m = 0; m < NS; ++m)
                    v += T2[(j-1)*256 + r16*16+m] * T2[(j-1)*256 + m*16+c16];
                T2[j*256 + tid] = v;
            }
            __syncthreads();
        }
        if (bid < 8) {
            for (int v4 = 0; v4 < 4; ++v4) {
                const int j2 = 4*bid + v4 + 1;   // 1..32
                float* Vc = V0; float* Vn = V1;
                bool have = false;
                for (int bit = 0; bit < 6; ++bit) {
                    if (!((j2 >> bit) & 1)) continue;
                    if (!have) {
                        if (tid < 256) Vc[tid] = S2[bit*256 + tid];
                        have = true;
                        __syncthreads();
                    } else {
                        float v = 0.f;
                        if (tid < 256) {
                            #pragma unroll
                            for (int m = 0; m < NS; ++m)
                                v += Vc[r16*16+m] * S2[bit*256 + m*16+c16];
                        }
                        __syncthreads();
                        if (tid < 256) Vn[tid] = v;
                        __syncthreads();
                        float* tt = Vc; Vc = Vn; Vn = tt;
                    }
                }
                if (tid < 256) ws[OFF_P + (j2-1)*256 + tid] = Vc[tid];
                __syncthreads();
            }
        } else {
            for (int v4 = 0; v4 < 4; ++v4) {
                const int k = 4*(bid-8) + v4;    // 0..127
                float* Vc = V0; float* Vn = V1;
                bool have = false;
                for (int bit = 0; bit < 7; ++bit) {
                    if (!((k >> bit) & 1)) continue;
                    if (!have) {
                        if (tid < 256) Vc[tid] = T2[bit*256 + tid];
                        have = true;
                        __syncthreads();
                    } else {
                        float v = 0.f;
                        if (tid < 256) {
                            #pragma unroll
                            for (int m = 0; m < NS; ++m)
                                v += Vc[r16*16+m] * T2[bit*256 + m*16+c16];
                        }
                        __syncthreads();
                        if (tid < 256) Vn[tid] = v;
                        __syncthreads();
                        float* tt = Vc; Vc = Vn; Vn = tt;
                    }
                }
                if (tid < 256) ws[OFF_Q + k*256 + tid] = have ? Vc[tid] : ident;
                __syncthreads();
            }
        }
    }
}

// ---------- K2: cin via Q-table sum (32 groups), correction, out-GEMM ----------
// (round-11 proven, unchanged)
__global__ __launch_bounds__(512, 4) void k2_kernel(const float* __restrict__ C,
                                                    const float* __restrict__ state,
                                                    const float* __restrict__ ws,
                                                    float* __restrict__ out) {
    __shared__ __align__(16) float st[32*20];     // padded stride 20
    __shared__ float vec[(NCH+1)*16];             // lend_0..c-1, state0
    __shared__ float part[32*17];
    __shared__ float cin_s[16];
    const int tid = threadIdx.x;
    const int row0 = blockIdx.x * 32;
    const int b = row0 >> 12, cch = (row0 >> 5) & (NCH-1);

    if (tid < 128) {
        const int j = tid >> 2, n4 = (tid & 3)*4;
        *(float4*)(&st[j*20 + n4]) =
            *(const float4*)(ws + OFF_U + (size_t)(row0 + j)*16 + n4);
    }
    for (int i = tid; i < cch*16; i += 512)
        vec[i] = ws[OFF_LEND + b*NCH*16 + i];
    if (tid < 16) vec[cch*16 + tid] = state[b*16 + tid];
    __syncthreads();

    {
        const int g = tid >> 4, n2 = tid & 15;
        float p = 0.f;
        for (int j = g; j <= cch; j += 32) {
            const int qidx = (j == cch) ? cch : (cch - 1 - j);
            const float* Q = ws + OFF_Q + qidx*256;
            float sv = 0.f;
            #pragma unroll
            for (int m = 0; m < NS; ++m) sv += vec[j*16 + m] * Q[m*16 + n2];
            p += sv;
        }
        part[g*17 + n2] = p;
    }
    __syncthreads();
    for (int s2 = 16; s2 > 0; s2 >>= 1) {
        if ((tid >> 4) < s2)
            part[(tid>>4)*17 + (tid&15)] += part[((tid>>4)+s2)*17 + (tid&15)];
        __syncthreads();
    }
    if (tid < 16) cin_s[tid] = part[tid];
    __syncthreads();

    if (tid < 128) {
        const int j = tid >> 2, n4 = (tid & 3)*4;
        float4 ls = *(const float4*)(&st[j*20 + n4]);
        const float* P = ws + OFF_P + j*256 + n4;
        float cx=0.f, cy=0.f, cz=0.f, cw=0.f;
        #pragma unroll
        for (int m = 0; m < NS; ++m) {
            const float cm = cin_s[m];
            float4 pv = *(const float4*)(P + m*16);
            cx += cm*pv.x; cy += cm*pv.y; cz += cm*pv.z; cw += cm*pv.w;
        }
        *(float4*)(&st[j*20 + n4]) = make_float4(ls.x+cx, ls.y+cy, ls.z+cz, ls.w+cw);
    }
    __syncthreads();
    if (cch == NCH-1 && tid < 16)
        out[(size_t)ROWS*HID + b*16 + tid] = st[31*20 + tid];

    const int w = tid >> 6, lane = tid & 63;
    const int rhalf = w & 1, cg = w >> 1;
    const int lr = lane & 15;
    const int hi = lane >> 4;
    const int lk = hi * 8;

    v8bf afr = {};
    if (lk < 16) {
        float4 s0 = *(const float4*)(&st[(rhalf*16 + lr)*20 + lk]);
        float4 s1 = *(const float4*)(&st[(rhalf*16 + lr)*20 + lk + 4]);
        afr[0]=(__bf16)s0.x; afr[1]=(__bf16)s0.y; afr[2]=(__bf16)s0.z; afr[3]=(__bf16)s0.w;
        afr[4]=(__bf16)s1.x; afr[5]=(__bf16)s1.y; afr[6]=(__bf16)s1.z; afr[7]=(__bf16)s1.w;
    }
    const int orow = row0 + rhalf*16 + hi*4;

    float4 pc0, pc1;
    {
        const int n0 = (cg*16)*16;
        if (lk < 16) {
            pc0 = *(const float4*)(C + (size_t)(n0 + lr)*16 + lk);
            pc1 = *(const float4*)(C + (size_t)(n0 + lr)*16 + lk + 4);
        }
    }
    #pragma unroll 4
    for (int nt = 0; nt < 16; ++nt) {
        const int n0 = (cg*16 + nt)*16;
        float4 c0 = pc0, c1 = pc1;
        if (nt + 1 < 16 && lk < 16) {
            const int n1 = (cg*16 + nt + 1)*16;
            pc0 = *(const float4*)(C + (size_t)(n1 + lr)*16 + lk);
            pc1 = *(const float4*)(C + (size_t)(n1 + lr)*16 + lk + 4);
        }
        v8bf bfr = {};
        if (lk < 16) {
            bfr[0]=(__bf16)c0.x; bfr[1]=(__bf16)c0.y; bfr[2]=(__bf16)c0.z; bfr[3]=(__bf16)c0.w;
            bfr[4]=(__bf16)c1.x; bfr[5]=(__bf16)c1.y; bfr[6]=(__bf16)c1.z; bfr[7]=(__bf16)c1.w;
        }
        f32x4 acc2 = {0.f, 0.f, 0.f, 0.f};
        acc2 = __builtin_amdgcn_mfma_f32_16x16x32_bf16(afr, bfr, acc2, 0, 0, 0);
        #pragma unroll
        for (int rg = 0; rg < 4; ++rg)
            out[(size_t)(orow + rg)*HID + n0 + lr] = acc2[rg];
    }
}

extern "C" void kernel_launch(void* const* d_in, const int* in_sizes, int n_in,
                              void* d_out, int out_size, void* d_ws, size_t ws_size,
                              hipStream_t stream) {
    (void)in_sizes; (void)n_in; (void)out_size; (void)ws_size;
    const float* x      = (const float*)d_in[0];
    const float* state  = (const float*)d_in[1];
    const float* A      = (const float*)d_in[2];
    const float* B      = (const float*)d_in[3];
    const float* C      = (const float*)d_in[4];
    const float* log_dt = (const float*)d_in[5];
    float* out = (float*)d_out;
    float* ws  = (float*)d_ws;

    k1_fused<<<ROWS/32, 512, 0, stream>>>(x, A, B, log_dt, ws);
    k2_kernel<<<ROWS/32, 512, 0, stream>>>(C, state, ws, out);
}